// Round 6
// baseline (2814.824 us; speedup 1.0000x reference)
//
#include <hip/hip_runtime.h>
#include <hip/hip_bf16.h>
#include <math.h>

#define B_ 128
#define S_ 256
#define A_ 8
#define E_ 300
#define H_ 300
#define KPAD 320
#define NGU 16     // unit groups per direction
#define NCOL 80    // padded gate-cols per unit group (<=80 real)
#define NBLK 128   // 8 pods (dir2 x gb4) x 16 unit-groups
#define GST 82     // gatesLds row stride (f32)

typedef unsigned short u16;
typedef unsigned int u32;
typedef unsigned long long u64;
typedef __attribute__((ext_vector_type(8))) short short8;
typedef __attribute__((ext_vector_type(4))) float floatx4;
typedef __attribute__((ext_vector_type(4))) unsigned int u32x4;

#define MFMA16(a, b, c) __builtin_amdgcn_mfma_f32_16x16x32_bf16((a), (b), (c), 0, 0, 0)
#define LD4_SC0(d, a) asm volatile("global_load_dwordx4 %0, %1, off sc0" : "=v"(d) : "v"(a) : "memory")
#define LD2_SC0(d, a) asm volatile("global_load_dwordx2 %0, %1, off sc0" : "=v"(d) : "v"(a) : "memory")

__device__ __host__ __forceinline__ int gu_cnt(int g) { return g < 6 ? 20 : 18; }
__device__ __host__ __forceinline__ int gu_u0(int g) { return g < 6 ? 20 * g : 120 + 18 * (g - 6); }

// ---- workspace layout (bytes) ----
static constexpr size_t oLens = 0;                       // mem_len[128], left_len[128], asp_len[128]
static constexpr size_t oMemX = 331776;                  // x bf16 [dir2][128][256][320] = 41943040
static constexpr size_t oWp   = 42274816;                // packed W bf16 [2][16][80][640] = 3276800
static constexpr size_t oBp   = 45551616;                // packed bias f32 [2][16][80] = 10240
static constexpr size_t oMemV = 45561856;                // locationed memory v f32 [128][256][600] = 78643200
static constexpr size_t oIT   = 124205056;               // i^T f32 [601][128]
static constexpr size_t oGi   = 124512768;               // gi^T f32 [900][128]
static constexpr size_t oGh   = 124973568;               // gh^T f32 [900][128]
static constexpr size_t oEt   = 125434368;               // et^T f32 [300][128]
static constexpr size_t oSc   = 125587968;               // scores f32 [128][256]
static constexpr size_t oHTP  = 125719040;               // tagged h u64 (plain copy) [par2][dir2][128][160] = 655360
static constexpr size_t oHTS  = 126374400;               // tagged h u64 (agent mirror, ALWAYS written) = 655360
static constexpr size_t WS_NEED = 127029760;             // ~121 MB

__device__ __forceinline__ u16 f2bf(float f) {
  union { float f; unsigned u; } v; v.f = f;
  unsigned r = (v.u + 0x7FFFu + ((v.u >> 16) & 1u)) >> 16;
  return (u16)r;
}
__device__ __forceinline__ float sigm(float x) { return 1.f / (1.f + __expf(-x)); }
__device__ __forceinline__ float tanh_f(float x) {
  x = fminf(15.f, fmaxf(-15.f, x));
  float e = __expf(2.f * x);
  return (e - 1.f) / (e + 1.f);
}

// ---------------- K1: lengths + zero init ----------------
__global__ __launch_bounds__(256) void init_kernel(const int* __restrict__ text,
                                                   const int* __restrict__ aspect,
                                                   const int* __restrict__ leftc,
                                                   char* __restrict__ ws) {
  const int bid = blockIdx.x, tid = threadIdx.x;
  if (bid == 0) {
    if (tid < B_) {
      int c = 0; const int* p = text + tid * S_;
      for (int s = 0; s < S_; ++s) c += (p[s] != 0);
      ((int*)(ws + oLens))[tid] = c;
    }
  } else if (bid == 1) {
    if (tid < B_) {
      int c = 0; const int* p = leftc + tid * S_;
      for (int s = 0; s < S_; ++s) c += (p[s] != 0);
      ((int*)(ws + oLens + 512))[tid] = c;
    }
  } else if (bid == 2) {
    if (tid < B_) {
      int c = 0; const int* p = aspect + tid * A_;
      for (int s = 0; s < A_; ++s) c += (p[s] != 0);
      ((int*)(ws + oLens + 1024))[tid] = c;
    }
  } else {
    const int T1 = 163840, T2 = 163840, EW = 38400;   // tagged h x2 (u32 counts) + et
    const int total = T1 + T2 + EW;
    for (int i = (bid - 3) * 256 + tid; i < total; i += 64 * 256) {
      int j = i;
      if (j < T1) { ((u32*)(ws + oHTP))[j] = 0u; continue; }  j -= T1;
      if (j < T2) { ((u32*)(ws + oHTS))[j] = 0u; continue; }  j -= T2;
      ((u32*)(ws + oEt))[j] = 0u;
    }
  }
}

// ---------------- K2: weight/bias pre-pack to bf16 ----------------
__global__ __launch_bounds__(256) void pack_kernel(
    const float* __restrict__ WihF, const float* __restrict__ WhhF,
    const float* __restrict__ bihF, const float* __restrict__ bhhF,
    const float* __restrict__ WihB, const float* __restrict__ WhhB,
    const float* __restrict__ bihB, const float* __restrict__ bhhB,
    char* __restrict__ ws) {
  const int WTOT = 2 * NGU * NCOL * 640;
  int idx = blockIdx.x * 256 + threadIdx.x;
  if (idx < WTOT) {
    int k = idx % 640;
    int n = (idx / 640) % NCOL;
    int g = (idx / (640 * NCOL)) % NGU;
    int dir = idx / (640 * NCOL * NGU);
    float v = 0.f;
    const int cnt = gu_cnt(g), u0 = gu_u0(g);
    if (n < cnt * 4) {
      int col = (n & 3) * 300 + u0 + (n >> 2);
      const float* Wih = dir ? WihB : WihF;
      const float* Whh = dir ? WhhB : WhhF;
      if (k < 300)                  v = Wih[(size_t)col * 300 + k];
      else if (k >= 320 && k < 620) v = Whh[(size_t)col * 300 + (k - 320)];
    }
    ((u16*)(ws + oWp))[idx] = f2bf(v);
  } else {
    int j = idx - WTOT;
    if (j < 2 * NGU * NCOL) {
      int n = j % NCOL; int g = (j / NCOL) % NGU; int dir = j / (NCOL * NGU);
      float v = 0.f;
      const int cnt = gu_cnt(g), u0 = gu_u0(g);
      if (n < cnt * 4) {
        int col = (n & 3) * 300 + u0 + (n >> 2);
        v = (dir ? bihB : bihF)[col] + (dir ? bhhB : bhhF)[col];
      }
      ((float*)(ws + oBp))[j] = v;
    }
  }
}

// ---------------- K3: embedding gather (bwd dir pre-reversed) ----------------
__global__ __launch_bounds__(KPAD) void gather_kernel(const int* __restrict__ text,
                                                      const float* __restrict__ emb,
                                                      char* __restrict__ ws) {
  const int bid = blockIdx.x;
  const int t = bid & 255;
  const int b = (bid >> 8) & 127;
  const int dir = bid >> 15;
  const int len = ((const int*)(ws + oLens))[b];
  const int tp = (dir == 0) ? t : ((t < len) ? (len - 1 - t) : t);
  const int tok = text[b * S_ + tp];
  u16* dst = (u16*)(ws + oMemX) + ((size_t)((dir * B_ + b) * S_ + t)) * KPAD;
  const float* src = emb + (size_t)tok * E_;
  const int k = threadIdx.x;
  float v = (k < E_) ? src[k] : 0.f;
  dst[k] = f2bf(v);
}

// ---------------- K4: persistent BiLSTM — direct tagged A-frag loads ----------------
// R5 post-mortem: protocol details, drains, and LDS conflicts all exonerated —
// the invariant cost is the serial phase chain per step. This version cuts it:
//  * NO hLds stash, NO barrier B2: each lane loads its MFMA A-fragment
//    DIRECTLY from the tagged global buffer (4 u64 words = 1 frag; tag
//    validated in-register, payload repacked with 2 movs). Pad words (>=150)
//    need no masking: their W columns are zero-packed.
//  * plain-only sentinel poll (~250cy/iter, own L2) — baseline's proven fast
//    poll — with an agent-mirror check every 8th iter (placement safety).
//    Validate retries: plain x2 then mirror (always complete => no deadlock).
//  * producer side byte-identical to passing R4/R5: dual publish of tagged
//    u64 (plain + relaxed agent mirror), tag rides with data, no drains.
//  * 2 barriers/step (B1 gate-release, B3 gates-visible). B1 doubles as the
//    "all cells done reading gatesLds" fence for the next stage-write.
__global__ __launch_bounds__(256, 1) void lstm_kernel(char* __restrict__ ws) {
  const int bid = (int)blockIdx.x;
  const int pod = bid & 7;              // {dir, gb}
  const int dir = pod >> 2;
  const int gb  = pod & 3;
  const int g   = bid >> 3;             // unit group 0..15
  const int cnt = gu_cnt(g), u0 = gu_u0(g);
  const int npair = cnt >> 1;           // 10 or 9
  const int tid = threadIdx.x;
  const int wv = tid >> 6;              // 0..3
  const int lane = tid & 63;
  const int quad = lane >> 4;
  const int l16 = lane & 15;
  const int Mtile = wv >> 1;            // rows [Mtile*16, +16)
  const int nt0 = (wv & 1) ? 3 : 0;     // N-tile set {0,1,2} or {3,4}
  const int ntc = (wv & 1) ? 2 : 3;

  const u16* __restrict__ Wg = (const u16*)(ws + oWp) + (size_t)(dir * NGU + g) * NCOL * 640;
  const float* __restrict__ Bpk = (const float*)(ws + oBp) + (dir * NGU + g) * NCOL;
  const u16* __restrict__ memx = (const u16*)(ws + oMemX) + (size_t)dir * B_ * S_ * KPAD;
  u64* __restrict__ hTP = (u64*)(ws + oHTP);
  u64* __restrict__ hTS = (u64*)(ws + oHTS);
  float* __restrict__ memv = (float*)(ws + oMemV);

  __shared__ float gatesLds[32 * GST];                     // 10496 B
  __shared__ float cS[640];
  __shared__ float hS[640];
  __shared__ float biasS[NCOL];
  __shared__ int lenS[32], llS[32], alS[32];

  for (int i = tid; i < 640; i += 256) { cS[i] = 0.f; hS[i] = 0.f; }
  if (tid < NCOL) biasS[tid] = Bpk[tid];
  if (tid < 32) {
    lenS[tid] = ((const int*)(ws + oLens))[gb * 32 + tid];
    llS[tid]  = ((const int*)(ws + oLens + 512))[gb * 32 + tid];
    alS[tid]  = ((const int*)(ws + oLens + 1024))[gb * 32 + tid];
  }

  // W fragments -> registers (once).
  short8 wx[10][3], wh[10][3];
  #pragma unroll
  for (int kk = 0; kk < 10; ++kk) {
    #pragma unroll
    for (int j = 0; j < 3; ++j) {
      if (j < ntc) {
        const u16* base = Wg + (size_t)((nt0 + j) * 16 + l16) * 640 + quad * 8;
        wx[kk][j] = *(const short8*)(base + kk * 32);
        wh[kk][j] = *(const short8*)(base + 320 + kk * 32);
      }
    }
  }
  __syncthreads();

  const int arow = gb * 32 + Mtile * 16 + l16;  // global batch row for A-frags
  // sentinel word for group (lane): first pair of the group, batch row gb*32
  const size_t sentoff = (size_t)(gb * 32) * 160 + (lane < 6 ? 10 * lane : 60 + 9 * (lane - 6));

  // prefetch x fragments for t = 0
  short8 xv[10];
  {
    const u16* xr = memx + ((size_t)arow * S_) * KPAD + quad * 8;
    #pragma unroll
    for (int kk = 0; kk < 10; ++kk) xv[kk] = *(const short8*)(xr + kk * 32);
  }

  for (int t = 0; t < S_; ++t) {
    const size_t parbase = ((size_t)(t & 1) * 2 + dir) * (B_ * 160);

    if (t > 0) {
      // ---- sentinel gate: wave 0, plain-only poll (fast); mirror every 8th ----
      if (wv == 0) {
        const u64* saP = hTP + parbase + sentoff;
        const u64* saS = hTS + parbase + sentoff;
        const u32 tgv = (u32)t;
        int itc = 0;
        while (true) {
          u64 svP = 0;
          if (lane < NGU) LD2_SC0(svP, saP);
          asm volatile("s_waitcnt vmcnt(0)" ::: "memory");
          __builtin_amdgcn_sched_barrier(0);
          bool ok = (lane >= NGU) || ((u32)(svP >> 32) == tgv);
          if (__all((int)ok)) break;
          if ((++itc & 7) == 0) {
            u64 svS = 0;
            if (lane < NGU)
              svS = __hip_atomic_load(saS, __ATOMIC_RELAXED, __HIP_MEMORY_SCOPE_AGENT);
            bool ok2 = (lane >= NGU) || ((u32)(svP >> 32) == tgv) || ((u32)(svS >> 32) == tgv);
            if (__all((int)ok2)) break;
          }
        }
      }
      asm volatile("s_barrier" ::: "memory");                // B1: gate open
    }

    // direct tagged A-frag loads: frag kk = words [quad*4+kk*16, +4) of arow
    u32x4 qa[10], qb[10];
    if (t > 0) {
      const u64* hrow = hTP + parbase + (size_t)arow * 160;
      #pragma unroll
      for (int kk = 0; kk < 10; ++kk) {
        const int wb = quad * 4 + kk * 16;
        LD4_SC0(qa[kk], hrow + wb);
        LD4_SC0(qb[kk], hrow + wb + 2);
      }
    }

    floatx4 acc[3];
    acc[0] = (floatx4){0.f, 0.f, 0.f, 0.f}; acc[1] = acc[0]; acc[2] = acc[0];
    // x-part MFMA (register operands) — overlaps the frag-load round trip
    #pragma unroll
    for (int kk = 0; kk < 10; ++kk) {
      #pragma unroll
      for (int j = 0; j < 3; ++j) {
        if (j < ntc)
          acc[j] = MFMA16(xv[kk], wx[kk][j], acc[j]);
      }
    }

    if (t > 0) {
      // validate tags in-register; stragglers: plain x2, then mirror
      const u32 tgv = (u32)t;
      asm volatile("s_waitcnt vmcnt(0)" ::: "memory");
      __builtin_amdgcn_sched_barrier(0);
      int tries = 0;
      while (true) {
        bool ok = true;
        #pragma unroll
        for (int kk = 0; kk < 10; ++kk) {
          const int wb = quad * 4 + kk * 16;
          ok = ok && ((qa[kk][1] == tgv) || (wb + 0 >= 150));
          ok = ok && ((qa[kk][3] == tgv) || (wb + 1 >= 150));
          ok = ok && ((qb[kk][1] == tgv) || (wb + 2 >= 150));
          ok = ok && ((qb[kk][3] == tgv) || (wb + 3 >= 150));
        }
        if (ok) break;
        ++tries;
        if (tries <= 2) {
          const u64* hrow = hTP + parbase + (size_t)arow * 160;
          #pragma unroll
          for (int kk = 0; kk < 10; ++kk) {
            const int wb = quad * 4 + kk * 16;
            LD4_SC0(qa[kk], hrow + wb);
            LD4_SC0(qb[kk], hrow + wb + 2);
          }
        } else {
          const u64* hrow = hTS + parbase + (size_t)arow * 160;
          #pragma unroll
          for (int kk = 0; kk < 10; ++kk) {
            const int wb = quad * 4 + kk * 16;
            u64 a0 = __hip_atomic_load(hrow + wb + 0, __ATOMIC_RELAXED, __HIP_MEMORY_SCOPE_AGENT);
            u64 a1 = __hip_atomic_load(hrow + wb + 1, __ATOMIC_RELAXED, __HIP_MEMORY_SCOPE_AGENT);
            u64 a2 = __hip_atomic_load(hrow + wb + 2, __ATOMIC_RELAXED, __HIP_MEMORY_SCOPE_AGENT);
            u64 a3 = __hip_atomic_load(hrow + wb + 3, __ATOMIC_RELAXED, __HIP_MEMORY_SCOPE_AGENT);
            qa[kk] = (u32x4){(u32)a0, (u32)(a0 >> 32), (u32)a1, (u32)(a1 >> 32)};
            qb[kk] = (u32x4){(u32)a2, (u32)(a2 >> 32), (u32)a3, (u32)(a3 >> 32)};
          }
        }
        asm volatile("s_waitcnt vmcnt(0)" ::: "memory");
        __builtin_amdgcn_sched_barrier(0);
      }

      // h-part MFMA: repack payloads to short8 A-frags, W from registers
      #pragma unroll
      for (int kk = 0; kk < 10; ++kk) {
        u32x4 pk = (u32x4){qa[kk][0], qa[kk][2], qb[kk][0], qb[kk][2]};
        const short8 av = *(const short8*)&pk;
        #pragma unroll
        for (int j = 0; j < 3; ++j) {
          if (j < ntc)
            acc[j] = MFMA16(av, wh[kk][j], acc[j]);
        }
      }
    }

    // stage gates to LDS (C layout: col=lane&15, row=quad*4+reg)
    #pragma unroll
    for (int j = 0; j < 3; ++j) {
      if (j < ntc) {
        const int colb = (nt0 + j) * 16 + l16;
        const int rb = Mtile * 16 + quad * 4;
        #pragma unroll
        for (int r = 0; r < 4; ++r)
          gatesLds[(rb + r) * GST + colb] = acc[j][r];
      }
    }
    asm volatile("s_waitcnt lgkmcnt(0)" ::: "memory");
    asm volatile("s_barrier" ::: "memory");          // B3: gates visible

    // elementwise LSTM cell: 32 rows * npair unit-pairs; DUAL publish per pair
    #pragma unroll
    for (int z = 0; z < 2; ++z) {
      const int it = tid + z * 256;
      if (it < 32 * npair) {
        const int bl = it & 31;
        const int pl = it >> 5;
        const int ul0 = pl * 2;
        const int len = lenS[bl];
        const bool m = (t < len);
        const float* gp = gatesLds + bl * GST + ul0 * 4;
        const float* bp = biasS + ul0 * 4;
        float h0K, h1K, h0N, h1N;
        {
          float ig = sigm(gp[0] + bp[0]);
          float fg = sigm(gp[1] + bp[1]);
          float gt = tanh_f(gp[2] + bp[2]);
          float og = sigm(gp[3] + bp[3]);
          float cOld = cS[ul0 * 32 + bl], hOld = hS[ul0 * 32 + bl];
          float cNew = fg * cOld + ig * gt;
          float hNew = og * tanh_f(cNew);
          cS[ul0 * 32 + bl] = m ? cNew : cOld;
          h0K = m ? hNew : hOld;
          hS[ul0 * 32 + bl] = h0K;
          h0N = m ? hNew : 0.f;
        }
        {
          float ig = sigm(gp[4] + bp[4]);
          float fg = sigm(gp[5] + bp[5]);
          float gt = tanh_f(gp[6] + bp[6]);
          float og = sigm(gp[7] + bp[7]);
          float cOld = cS[(ul0 + 1) * 32 + bl], hOld = hS[(ul0 + 1) * 32 + bl];
          float cNew = fg * cOld + ig * gt;
          float hNew = og * tanh_f(cNew);
          cS[(ul0 + 1) * 32 + bl] = m ? cNew : cOld;
          h1K = m ? hNew : hOld;
          hS[(ul0 + 1) * 32 + bl] = h1K;
          h1N = m ? hNew : 0.f;
        }
        const int bglob = gb * 32 + bl;
        u32 packed = (u32)f2bf(h0K) | ((u32)f2bf(h1K) << 16);
        u64 tg64 = (u64)packed | ((u64)(u32)(t + 1) << 32);
        const size_t hx = ((size_t)((t + 1) & 1) * 2 + dir) * (B_ * 160)
                        + (size_t)bglob * 160 + ((u0 + ul0) >> 1);
        *(volatile u64*)(hTP + hx) = tg64;                               // plain (own L2)
        __hip_atomic_store(&hTS[hx], tg64,
                           __ATOMIC_RELAXED, __HIP_MEMORY_SCOPE_AGENT);  // mirror (always)
        // locationed memory store
        int pos = (dir == 0) ? t : (m ? (len - 1 - t) : t);
        float ml = (float)len, ll = (float)llS[bl], al = (float)alS[bl];
        float p = (float)pos;
        float wl;
        if (p < ll) wl = 1.f - (ll - p) / ml;
        else if ((p >= ll + al) && (p < ml)) wl = 1.f - (p - ll - al + 1.f) / ml;
        else wl = 1.f;
        *(float2*)&memv[((size_t)bglob * S_ + pos) * 600 + dir * 300 + u0 + ul0] =
            make_float2(h0N * wl, h1N * wl);
      }
    }

    // next-step x prefetch (overlaps the coming poll window)
    if (t + 1 < S_) {
      const u16* xr = memx + ((size_t)arow * S_ + (t + 1)) * KPAD + quad * 8;
      #pragma unroll
      for (int kk = 0; kk < 10; ++kk) xv[kk] = *(const short8*)(xr + kk * 32);
    }
  }
}

// ---------------- K5: attention scores ----------------
__global__ __launch_bounds__(256) void score_kernel(const float* __restrict__ attW,
                                                    char* __restrict__ ws) {
  const int bid = blockIdx.x;
  const int b = bid >> 1, sh = bid & 1;
  const int tid = threadIdx.x, wv = tid >> 6, lane = tid & 63;
  __shared__ float aW[601];
  for (int i = tid; i < 601; i += 256) aW[i] = attW[i];
  const float* memv = (const float*)(ws + oMemV) + (size_t)b * S_ * 600;
  const float ml = (float)((const int*)(ws + oLens))[b];
  const float ll = (float)((const int*)(ws + oLens + 512))[b];
  const float al = (float)((const int*)(ws + oLens + 1024))[b];
  __syncthreads();
  float* scg = (float*)(ws + oSc) + b * S_;
  for (int s = sh * 128 + wv; s < sh * 128 + 128; s += 4) {
    const float* rowp = memv + (size_t)s * 600;
    float acc = 0.f;
    for (int d = lane; d < 600; d += 64) acc += rowp[d] * aW[d];
    for (int off = 32; off; off >>= 1) acc += __shfl_xor(acc, off);
    if (lane == 0) {
      float p = (float)s;
      bool inl = p < ll;
      bool inr = (p >= ll + al) && (p < ml);
      float u = inl ? (p - ll) : (inr ? (p - ll - al + 1.f) : 0.f);
      scg[s] = acc + u * aW[600];
    }
  }
}

// ---------------- K6: softmax + weighted sum -> i^T ----------------
__global__ __launch_bounds__(256) void attn_kernel(char* __restrict__ ws) {
  const int bid = blockIdx.x;
  const int b = bid >> 1, dh = bid & 1;
  const int tid = threadIdx.x, wv = tid >> 6, lane = tid & 63;
  __shared__ float alpha[256];
  __shared__ float red[8];
  const float* scg = (const float*)(ws + oSc) + b * S_;
  float v = scg[tid];
  float mx = v;
  for (int off = 32; off; off >>= 1) mx = fmaxf(mx, __shfl_xor(mx, off));
  if (lane == 0) red[wv] = mx;
  __syncthreads();
  mx = fmaxf(fmaxf(red[0], red[1]), fmaxf(red[2], red[3]));
  float e = __expf(v - mx);
  float sm = e;
  for (int off = 32; off; off >>= 1) sm += __shfl_xor(sm, off);
  if (lane == 0) red[4 + wv] = sm;
  __syncthreads();
  float tot = red[4] + red[5] + red[6] + red[7];
  alpha[tid] = e / tot;
  const float ml = (float)((const int*)(ws + oLens))[b];
  const float ll = (float)((const int*)(ws + oLens + 512))[b];
  const float al = (float)((const int*)(ws + oLens + 1024))[b];
  __syncthreads();
  const float* memv = (const float*)(ws + oMemV) + (size_t)b * S_ * 600;
  float* iT = (float*)(ws + oIT);
  const int d0 = dh * 301, d1 = dh ? 601 : 301;
  for (int d = d0 + tid; d < d1; d += 256) {
    float acc = 0.f;
    if (d < 600) {
      for (int s = 0; s < 256; ++s) acc += alpha[s] * memv[(size_t)s * 600 + d];
    } else {
      for (int s = 0; s < 256; ++s) {
        float p = (float)s;
        bool inl = p < ll;
        bool inr = (p >= ll + al) && (p < ml);
        float u = inl ? (p - ll) : (inr ? (p - ll - al + 1.f) : 0.f);
        acc += alpha[s] * u;
      }
    }
    iT[d * 128 + b] = acc;
  }
}

// ---------------- K7: GRU gi (once) ----------------
__global__ __launch_bounds__(256) void gi_kernel(const float* __restrict__ Wih,
                                                 const float* __restrict__ bih,
                                                 char* __restrict__ ws) {
  int idx = blockIdx.x * 256 + threadIdx.x;
  int r = idx >> 7, b = idx & 127;
  if (r >= 900) return;
  const float* iT = (const float*)(ws + oIT);
  const float* wr = Wih + (size_t)r * 601;
  float acc = bih[r];
  for (int d = 0; d < 601; ++d) acc += iT[d * 128 + b] * wr[d];
  ((float*)(ws + oGi))[r * 128 + b] = acc;
}

// ---------------- K8: GRU gh (per hop) ----------------
__global__ __launch_bounds__(256) void gh_kernel(const float* __restrict__ Whh,
                                                 const float* __restrict__ bhh,
                                                 char* __restrict__ ws) {
  int idx = blockIdx.x * 256 + threadIdx.x;
  int r = idx >> 7, b = idx & 127;
  if (r >= 900) return;
  const float* et = (const float*)(ws + oEt);
  const float* wr = Whh + (size_t)r * 300;
  float acc = bhh[r];
  for (int u = 0; u < 300; ++u) acc += et[u * 128 + b] * wr[u];
  ((float*)(ws + oGh))[r * 128 + b] = acc;
}

// ---------------- K9: GRU update (per hop) ----------------
__global__ __launch_bounds__(256) void up_kernel(char* __restrict__ ws) {
  int idx = blockIdx.x * 256 + threadIdx.x;
  int u = idx >> 7, b = idx & 127;
  if (u >= 300) return;
  const float* gi = (const float*)(ws + oGi);
  const float* gh = (const float*)(ws + oGh);
  float* et = (float*)(ws + oEt);
  float rr = sigm(gi[u * 128 + b] + gh[u * 128 + b]);
  float zz = sigm(gi[(300 + u) * 128 + b] + gh[(300 + u) * 128 + b]);
  float nn = tanh_f(gi[(600 + u) * 128 + b] + rr * gh[(600 + u) * 128 + b]);
  float old = et[u * 128 + b];
  et[u * 128 + b] = (1.f - zz) * nn + zz * old;
}

// ---------------- K10: dense head ----------------
__global__ __launch_bounds__(384) void dense_kernel(const float* __restrict__ dW,
                                                    const float* __restrict__ dB,
                                                    float* __restrict__ out,
                                                    const char* __restrict__ ws) {
  int tid = threadIdx.x;
  if (tid >= 384) return;
  int b = tid / 3, c = tid - 3 * (tid / 3);
  const float* et = (const float*)(ws + oEt);
  float acc = dB[c];
  const float* wr = dW + c * 300;
  for (int u = 0; u < 300; ++u) acc += et[u * 128 + b] * wr[u];
  out[b * 3 + c] = acc;
}

extern "C" void kernel_launch(void* const* d_in, const int* in_sizes, int n_in,
                              void* d_out, int out_size, void* d_ws, size_t ws_size,
                              hipStream_t stream) {
  const int* text = (const int*)d_in[0];
  const int* aspect = (const int*)d_in[1];
  const int* leftc = (const int*)d_in[2];
  const float* emb = (const float*)d_in[3];
  const float* WihF = (const float*)d_in[4];
  const float* WhhF = (const float*)d_in[5];
  const float* bihF = (const float*)d_in[6];
  const float* bhhF = (const float*)d_in[7];
  const float* WihB = (const float*)d_in[8];
  const float* WhhB = (const float*)d_in[9];
  const float* bihB = (const float*)d_in[10];
  const float* bhhB = (const float*)d_in[11];
  const float* attW = (const float*)d_in[12];
  const float* gruWih = (const float*)d_in[14];
  const float* gruWhh = (const float*)d_in[15];
  const float* gruBih = (const float*)d_in[16];
  const float* gruBhh = (const float*)d_in[17];
  const float* denseW = (const float*)d_in[18];
  const float* denseB = (const float*)d_in[19];
  float* out = (float*)d_out;
  char* ws = (char*)d_ws;
  if (ws_size < WS_NEED) return;

  init_kernel<<<67, 256, 0, stream>>>(text, aspect, leftc, ws);
  pack_kernel<<<6420, 256, 0, stream>>>(WihF, WhhF, bihF, bhhF, WihB, WhhB, bihB, bhhB, ws);
  gather_kernel<<<2 * B_ * S_, KPAD, 0, stream>>>(text, emb, ws);
  lstm_kernel<<<NBLK, 256, 0, stream>>>(ws);
  score_kernel<<<2 * B_, 256, 0, stream>>>(attW, ws);
  attn_kernel<<<2 * B_, 256, 0, stream>>>(ws);
  gi_kernel<<<450, 256, 0, stream>>>(gruWih, gruBih, ws);
  for (int h = 0; h < 3; ++h) {
    gh_kernel<<<450, 256, 0, stream>>>(gruWhh, gruBhh, ws);
    up_kernel<<<150, 256, 0, stream>>>(ws);
  }
  dense_kernel<<<1, 384, 0, stream>>>(denseW, denseB, out, ws);
}

// Round 7
// 2586.734 us; speedup vs baseline: 1.0882x; 1.0882x over previous
//
#include <hip/hip_runtime.h>
#include <hip/hip_bf16.h>
#include <math.h>

#define B_ 128
#define S_ 256
#define A_ 8
#define E_ 300
#define H_ 300
#define KPAD 320
#define NGU 16     // unit groups per direction
#define NCOL 80    // padded gate-cols per unit group (<=80 real)
#define HROW 328   // LDS row stride (u16) for h panel (320 + 8 pad)
#define NBLK 128   // 8 pods (dir2 x gb4) x 16 unit-groups
#define GST 82     // gatesLds row stride (f32)

typedef unsigned short u16;
typedef unsigned int u32;
typedef unsigned long long u64;
typedef __attribute__((ext_vector_type(8))) short short8;
typedef __attribute__((ext_vector_type(4))) float floatx4;
typedef __attribute__((ext_vector_type(4))) unsigned int u32x4;

#define MFMA16(a, b, c) __builtin_amdgcn_mfma_f32_16x16x32_bf16((a), (b), (c), 0, 0, 0)

__device__ __host__ __forceinline__ int gu_cnt(int g) { return g < 6 ? 20 : 18; }
__device__ __host__ __forceinline__ int gu_u0(int g) { return g < 6 ? 20 * g : 120 + 18 * (g - 6); }

// ---- workspace layout (bytes) ----
static constexpr size_t oLens = 0;                       // mem_len[128], left_len[128], asp_len[128]
static constexpr size_t oMemX = 331776;                  // x bf16 [dir2][128][256][320] = 41943040
static constexpr size_t oWp   = 42274816;                // packed W bf16 [2][16][80][640] = 3276800
static constexpr size_t oBp   = 45551616;                // packed bias f32 [2][16][80] = 10240
static constexpr size_t oMemV = 45561856;                // locationed memory v f32 [128][256][600] = 78643200
static constexpr size_t oIT   = 124205056;               // i^T f32 [601][128]
static constexpr size_t oGi   = 124512768;               // gi^T f32 [900][128]
static constexpr size_t oGh   = 124973568;               // gh^T f32 [900][128]
static constexpr size_t oEt   = 125434368;               // et^T f32 [300][128]
static constexpr size_t oSc   = 125587968;               // scores f32 [128][256]
static constexpr size_t oHT   = 126374400;               // tagged h u64 (agent-scope, SINGLE copy) [par2][dir2][128][160] = 655360
static constexpr size_t WS_NEED = 127029760;             // ~121 MB

__device__ __forceinline__ u16 f2bf(float f) {
  union { float f; unsigned u; } v; v.f = f;
  unsigned r = (v.u + 0x7FFFu + ((v.u >> 16) & 1u)) >> 16;
  return (u16)r;
}
__device__ __forceinline__ float sigm(float x) { return 1.f / (1.f + __expf(-x)); }
__device__ __forceinline__ float tanh_f(float x) {
  x = fminf(15.f, fmaxf(-15.f, x));
  float e = __expf(2.f * x);
  return (e - 1.f) / (e + 1.f);
}

// tags live in q[i][1] (even col) and q[i][3] (odd col); payload in [0]/[2].
// u64 cols >= 150 are pad (never written): tag don't-care.
__device__ __forceinline__ bool tags_ok(const u32x4 (&q)[10], u32 tgv, int scol0) {
  bool ok = true;
  #pragma unroll
  for (int i = 0; i < 10; ++i) {
    ok = ok && ((q[i][1] == tgv) || (scol0 + 2 * i >= 150));
    ok = ok && ((q[i][3] == tgv) || (scol0 + 2 * i + 1 >= 150));
  }
  return ok;
}
__device__ __forceinline__ void load_mirror(u32x4 (&q)[10], const u64* sp) {
  #pragma unroll
  for (int i = 0; i < 10; ++i) {
    u64 lo = __hip_atomic_load(sp + 2 * i, __ATOMIC_RELAXED, __HIP_MEMORY_SCOPE_AGENT);
    u64 hi = __hip_atomic_load(sp + 2 * i + 1, __ATOMIC_RELAXED, __HIP_MEMORY_SCOPE_AGENT);
    q[i] = (u32x4){(u32)lo, (u32)(lo >> 32), (u32)hi, (u32)(hi >> 32)};
  }
}

// ---------------- K1: lengths + zero init ----------------
__global__ __launch_bounds__(256) void init_kernel(const int* __restrict__ text,
                                                   const int* __restrict__ aspect,
                                                   const int* __restrict__ leftc,
                                                   char* __restrict__ ws) {
  const int bid = blockIdx.x, tid = threadIdx.x;
  if (bid == 0) {
    if (tid < B_) {
      int c = 0; const int* p = text + tid * S_;
      for (int s = 0; s < S_; ++s) c += (p[s] != 0);
      ((int*)(ws + oLens))[tid] = c;
    }
  } else if (bid == 1) {
    if (tid < B_) {
      int c = 0; const int* p = leftc + tid * S_;
      for (int s = 0; s < S_; ++s) c += (p[s] != 0);
      ((int*)(ws + oLens + 512))[tid] = c;
    }
  } else if (bid == 2) {
    if (tid < B_) {
      int c = 0; const int* p = aspect + tid * A_;
      for (int s = 0; s < A_; ++s) c += (p[s] != 0);
      ((int*)(ws + oLens + 1024))[tid] = c;
    }
  } else {
    const int T1 = 163840, EW = 38400;   // tagged h (u32 count) + et
    const int total = T1 + EW;
    for (int i = (bid - 3) * 256 + tid; i < total; i += 64 * 256) {
      int j = i;
      if (j < T1) { ((u32*)(ws + oHT))[j] = 0u; continue; }  j -= T1;
      ((u32*)(ws + oEt))[j] = 0u;
    }
  }
}

// ---------------- K2: weight/bias pre-pack to bf16 ----------------
__global__ __launch_bounds__(256) void pack_kernel(
    const float* __restrict__ WihF, const float* __restrict__ WhhF,
    const float* __restrict__ bihF, const float* __restrict__ bhhF,
    const float* __restrict__ WihB, const float* __restrict__ WhhB,
    const float* __restrict__ bihB, const float* __restrict__ bhhB,
    char* __restrict__ ws) {
  const int WTOT = 2 * NGU * NCOL * 640;
  int idx = blockIdx.x * 256 + threadIdx.x;
  if (idx < WTOT) {
    int k = idx % 640;
    int n = (idx / 640) % NCOL;
    int g = (idx / (640 * NCOL)) % NGU;
    int dir = idx / (640 * NCOL * NGU);
    float v = 0.f;
    const int cnt = gu_cnt(g), u0 = gu_u0(g);
    if (n < cnt * 4) {
      int col = (n & 3) * 300 + u0 + (n >> 2);
      const float* Wih = dir ? WihB : WihF;
      const float* Whh = dir ? WhhB : WhhF;
      if (k < 300)                  v = Wih[(size_t)col * 300 + k];
      else if (k >= 320 && k < 620) v = Whh[(size_t)col * 300 + (k - 320)];
    }
    ((u16*)(ws + oWp))[idx] = f2bf(v);
  } else {
    int j = idx - WTOT;
    if (j < 2 * NGU * NCOL) {
      int n = j % NCOL; int g = (j / NCOL) % NGU; int dir = j / (NCOL * NGU);
      float v = 0.f;
      const int cnt = gu_cnt(g), u0 = gu_u0(g);
      if (n < cnt * 4) {
        int col = (n & 3) * 300 + u0 + (n >> 2);
        v = (dir ? bihB : bihF)[col] + (dir ? bhhB : bhhF)[col];
      }
      ((float*)(ws + oBp))[j] = v;
    }
  }
}

// ---------------- K3: embedding gather (bwd dir pre-reversed) ----------------
__global__ __launch_bounds__(KPAD) void gather_kernel(const int* __restrict__ text,
                                                      const float* __restrict__ emb,
                                                      char* __restrict__ ws) {
  const int bid = blockIdx.x;
  const int t = bid & 255;
  const int b = (bid >> 8) & 127;
  const int dir = bid >> 15;
  const int len = ((const int*)(ws + oLens))[b];
  const int tp = (dir == 0) ? t : ((t < len) ? (len - 1 - t) : t);
  const int tok = text[b * S_ + tp];
  u16* dst = (u16*)(ws + oMemX) + ((size_t)((dir * B_ + b) * S_ + t)) * KPAD;
  const float* src = emb + (size_t)tok * E_;
  const int k = threadIdx.x;
  float v = (k < E_) ? src[k] : 0.f;
  dst[k] = f2bf(v);
}

// ---------------- K4: persistent BiLSTM — MIRROR-ONLY tagged exchange ----------------
// A/B experiment vs R5 (single variable): the plain own-L2 buffer is DELETED.
// If workgroup->XCD placement makes pod members remote, R5's plain-first
// ladders (sentinel: ~4 wasted plain iters before the every-8th mirror check;
// validate: 2 wasted plain retries) burn ~5000cy/step — this variant removes
// them. Protocol: producers publish each h-pair ONCE as a relaxed agent-scope
// tagged u64 (lo = 2xbf16, hi = step tag; tag rides with data -> no flags, no
// drains). Consumers: wave 0 sentinel-polls 16 mirror words; barrier; one-shot
// cooperative panel load (agent loads, overlapped by x-MFMA); per-word
// validate with mirror-only retries (producer skew ~100cy -> rare).
// W stays in registers (R5-proven, bank conflicts -77%). hLds stash + B2
// retained (R6 proved direct per-lane frag loads regress).
__global__ __launch_bounds__(256, 1) void lstm_kernel(char* __restrict__ ws) {
  const int bid = (int)blockIdx.x;
  const int pod = bid & 7;              // {dir, gb}
  const int dir = pod >> 2;
  const int gb  = pod & 3;
  const int g   = bid >> 3;             // unit group 0..15
  const int cnt = gu_cnt(g), u0 = gu_u0(g);
  const int npair = cnt >> 1;           // 10 or 9
  const int tid = threadIdx.x;
  const int wv = tid >> 6;              // 0..3
  const int lane = tid & 63;
  const int quad = lane >> 4;
  const int l16 = lane & 15;
  const int Mtile = wv >> 1;            // rows [Mtile*16, +16)
  const int nt0 = (wv & 1) ? 3 : 0;     // N-tile set {0,1,2} or {3,4}
  const int ntc = (wv & 1) ? 2 : 3;

  const u16* __restrict__ Wg = (const u16*)(ws + oWp) + (size_t)(dir * NGU + g) * NCOL * 640;
  const float* __restrict__ Bpk = (const float*)(ws + oBp) + (dir * NGU + g) * NCOL;
  const u16* __restrict__ memx = (const u16*)(ws + oMemX) + (size_t)dir * B_ * S_ * KPAD;
  u64* __restrict__ hT = (u64*)(ws + oHT);
  float* __restrict__ memv = (float*)(ws + oMemV);

  __shared__ __align__(16) u16 hLds[32 * HROW];            // 20992 B
  __shared__ float gatesLds[32 * GST];                     // 10496 B
  __shared__ float cS[640];
  __shared__ float hS[640];
  __shared__ float biasS[NCOL];
  __shared__ int lenS[32], llS[32], alS[32];

  for (int i = tid; i < 640; i += 256) { cS[i] = 0.f; hS[i] = 0.f; }
  for (int i = tid; i < 32 * HROW / 2; i += 256) ((u32*)hLds)[i] = 0u;
  if (tid < NCOL) biasS[tid] = Bpk[tid];
  if (tid < 32) {
    lenS[tid] = ((const int*)(ws + oLens))[gb * 32 + tid];
    llS[tid]  = ((const int*)(ws + oLens + 512))[gb * 32 + tid];
    alS[tid]  = ((const int*)(ws + oLens + 1024))[gb * 32 + tid];
  }

  // W fragments -> registers (once).
  short8 wx[10][3], wh[10][3];
  #pragma unroll
  for (int kk = 0; kk < 10; ++kk) {
    #pragma unroll
    for (int j = 0; j < 3; ++j) {
      if (j < ntc) {
        const u16* base = Wg + (size_t)((nt0 + j) * 16 + l16) * 640 + quad * 8;
        wx[kk][j] = *(const short8*)(base + kk * 32);
        wh[kk][j] = *(const short8*)(base + 320 + kk * 32);
      }
    }
  }
  __syncthreads();

  // GEMM fragment pointers
  const int row = gb * 32 + Mtile * 16 + l16;   // global batch row for A-frags
  const u16* hA = hLds + (Mtile * 16 + l16) * HROW + quad * 8;

  // panel-share geometry: 8 threads/row, 20 u64 cols per thread
  const int srow = tid >> 3;
  const int scol0 = (tid & 7) * 20;
  u16* sdst = hLds + srow * HROW + scol0 * 2;
  const size_t sboff = (size_t)(gb * 32 + srow) * 160 + scol0;
  // sentinel word for group (lane): first pair of the group, batch row gb*32
  const size_t sentoff = (size_t)(gb * 32) * 160 + (lane < 6 ? 10 * lane : 60 + 9 * (lane - 6));

  // prefetch x fragments for t = 0
  short8 xv[10];
  {
    const u16* xr = memx + ((size_t)row * S_) * KPAD + quad * 8;
    #pragma unroll
    for (int kk = 0; kk < 10; ++kk) xv[kk] = *(const short8*)(xr + kk * 32);
  }

  for (int t = 0; t < S_; ++t) {
    const size_t parbase = ((size_t)(t & 1) * 2 + dir) * (B_ * 160);

    if (t > 0) {
      // ---- sentinel gate: wave 0 polls 16 mirror tags (128 B/iter) ----
      if (wv == 0) {
        const u64* sa = hT + parbase + sentoff;
        const u32 tgv = (u32)t;
        while (true) {
          u64 sv = 0;
          if (lane < NGU)
            sv = __hip_atomic_load(sa, __ATOMIC_RELAXED, __HIP_MEMORY_SCOPE_AGENT);
          if (__all((int)(lane >= NGU || (u32)(sv >> 32) == tgv))) break;
        }
      }
      asm volatile("s_barrier" ::: "memory");                // B1: gate open
    }

    u32x4 q[10];
    if (t > 0) load_mirror(q, hT + parbase + sboff);         // one-shot panel load

    floatx4 acc[3];
    acc[0] = (floatx4){0.f, 0.f, 0.f, 0.f}; acc[1] = acc[0]; acc[2] = acc[0];
    // x-part MFMA (register operands) — overlaps the panel load round trip
    #pragma unroll
    for (int kk = 0; kk < 10; ++kk) {
      #pragma unroll
      for (int j = 0; j < 3; ++j) {
        if (j < ntc)
          acc[j] = MFMA16(xv[kk], wx[kk][j], acc[j]);
      }
    }

    if (t > 0) {
      // validate own tags; stragglers: mirror-only retries (rare, skew ~100cy)
      const u32 tgv = (u32)t;
      while (!tags_ok(q, tgv, scol0)) {
        load_mirror(q, hT + parbase + sboff);
      }
      // land payloads (tags stripped) into hLds: 5 x 16B stores
      #pragma unroll
      for (int i = 0; i < 10; i += 2) {
        u32x4 pk = (u32x4){q[i][0], q[i][2], q[i + 1][0], q[i + 1][2]};
        *(u32x4*)(sdst + 4 * i) = pk;
      }
    }

    asm volatile("s_waitcnt lgkmcnt(0)" ::: "memory");
    asm volatile("s_barrier" ::: "memory");          // B2: stash visible

    // h-part: A-frags from LDS, B-frags from registers
    #pragma unroll
    for (int kk = 0; kk < 10; ++kk) {
      const short8 av = *(const short8*)(hA + kk * 32);
      #pragma unroll
      for (int j = 0; j < 3; ++j) {
        if (j < ntc)
          acc[j] = MFMA16(av, wh[kk][j], acc[j]);
      }
    }

    // stage gates to LDS (C layout: col=lane&15, row=quad*4+reg)
    #pragma unroll
    for (int j = 0; j < 3; ++j) {
      if (j < ntc) {
        const int colb = (nt0 + j) * 16 + l16;
        const int rb = Mtile * 16 + quad * 4;
        #pragma unroll
        for (int r = 0; r < 4; ++r)
          gatesLds[(rb + r) * GST + colb] = acc[j][r];
      }
    }
    asm volatile("s_waitcnt lgkmcnt(0)" ::: "memory");
    asm volatile("s_barrier" ::: "memory");          // B3: gates visible

    // elementwise LSTM cell: 32 rows * npair unit-pairs; SINGLE tagged publish
    #pragma unroll
    for (int z = 0; z < 2; ++z) {
      const int it = tid + z * 256;
      if (it < 32 * npair) {
        const int bl = it & 31;
        const int pl = it >> 5;
        const int ul0 = pl * 2;
        const int len = lenS[bl];
        const bool m = (t < len);
        const float* gp = gatesLds + bl * GST + ul0 * 4;
        const float* bp = biasS + ul0 * 4;
        float h0K, h1K, h0N, h1N;
        {
          float ig = sigm(gp[0] + bp[0]);
          float fg = sigm(gp[1] + bp[1]);
          float gt = tanh_f(gp[2] + bp[2]);
          float og = sigm(gp[3] + bp[3]);
          float cOld = cS[ul0 * 32 + bl], hOld = hS[ul0 * 32 + bl];
          float cNew = fg * cOld + ig * gt;
          float hNew = og * tanh_f(cNew);
          cS[ul0 * 32 + bl] = m ? cNew : cOld;
          h0K = m ? hNew : hOld;
          hS[ul0 * 32 + bl] = h0K;
          h0N = m ? hNew : 0.f;
        }
        {
          float ig = sigm(gp[4] + bp[4]);
          float fg = sigm(gp[5] + bp[5]);
          float gt = tanh_f(gp[6] + bp[6]);
          float og = sigm(gp[7] + bp[7]);
          float cOld = cS[(ul0 + 1) * 32 + bl], hOld = hS[(ul0 + 1) * 32 + bl];
          float cNew = fg * cOld + ig * gt;
          float hNew = og * tanh_f(cNew);
          cS[(ul0 + 1) * 32 + bl] = m ? cNew : cOld;
          h1K = m ? hNew : hOld;
          hS[(ul0 + 1) * 32 + bl] = h1K;
          h1N = m ? hNew : 0.f;
        }
        const int bglob = gb * 32 + bl;
        u32 packed = (u32)f2bf(h0K) | ((u32)f2bf(h1K) << 16);
        u64 tg64 = (u64)packed | ((u64)(u32)(t + 1) << 32);
        const size_t hx = ((size_t)((t + 1) & 1) * 2 + dir) * (B_ * 160)
                        + (size_t)bglob * 160 + ((u0 + ul0) >> 1);
        __hip_atomic_store(&hT[hx], tg64,
                           __ATOMIC_RELAXED, __HIP_MEMORY_SCOPE_AGENT);
        // locationed memory store
        int pos = (dir == 0) ? t : (m ? (len - 1 - t) : t);
        float ml = (float)len, ll = (float)llS[bl], al = (float)alS[bl];
        float p = (float)pos;
        float wl;
        if (p < ll) wl = 1.f - (ll - p) / ml;
        else if ((p >= ll + al) && (p < ml)) wl = 1.f - (p - ll - al + 1.f) / ml;
        else wl = 1.f;
        *(float2*)&memv[((size_t)bglob * S_ + pos) * 600 + dir * 300 + u0 + ul0] =
            make_float2(h0N * wl, h1N * wl);
      }
    }

    // next-step x prefetch (overlaps the coming poll window)
    if (t + 1 < S_) {
      const u16* xr = memx + ((size_t)row * S_ + (t + 1)) * KPAD + quad * 8;
      #pragma unroll
      for (int kk = 0; kk < 10; ++kk) xv[kk] = *(const short8*)(xr + kk * 32);
    }
  }
}

// ---------------- K5: attention scores ----------------
__global__ __launch_bounds__(256) void score_kernel(const float* __restrict__ attW,
                                                    char* __restrict__ ws) {
  const int bid = blockIdx.x;
  const int b = bid >> 1, sh = bid & 1;
  const int tid = threadIdx.x, wv = tid >> 6, lane = tid & 63;
  __shared__ float aW[601];
  for (int i = tid; i < 601; i += 256) aW[i] = attW[i];
  const float* memv = (const float*)(ws + oMemV) + (size_t)b * S_ * 600;
  const float ml = (float)((const int*)(ws + oLens))[b];
  const float ll = (float)((const int*)(ws + oLens + 512))[b];
  const float al = (float)((const int*)(ws + oLens + 1024))[b];
  __syncthreads();
  float* scg = (float*)(ws + oSc) + b * S_;
  for (int s = sh * 128 + wv; s < sh * 128 + 128; s += 4) {
    const float* rowp = memv + (size_t)s * 600;
    float acc = 0.f;
    for (int d = lane; d < 600; d += 64) acc += rowp[d] * aW[d];
    for (int off = 32; off; off >>= 1) acc += __shfl_xor(acc, off);
    if (lane == 0) {
      float p = (float)s;
      bool inl = p < ll;
      bool inr = (p >= ll + al) && (p < ml);
      float u = inl ? (p - ll) : (inr ? (p - ll - al + 1.f) : 0.f);
      scg[s] = acc + u * aW[600];
    }
  }
}

// ---------------- K6: softmax + weighted sum -> i^T ----------------
__global__ __launch_bounds__(256) void attn_kernel(char* __restrict__ ws) {
  const int bid = blockIdx.x;
  const int b = bid >> 1, dh = bid & 1;
  const int tid = threadIdx.x, wv = tid >> 6, lane = tid & 63;
  __shared__ float alpha[256];
  __shared__ float red[8];
  const float* scg = (const float*)(ws + oSc) + b * S_;
  float v = scg[tid];
  float mx = v;
  for (int off = 32; off; off >>= 1) mx = fmaxf(mx, __shfl_xor(mx, off));
  if (lane == 0) red[wv] = mx;
  __syncthreads();
  mx = fmaxf(fmaxf(red[0], red[1]), fmaxf(red[2], red[3]));
  float e = __expf(v - mx);
  float sm = e;
  for (int off = 32; off; off >>= 1) sm += __shfl_xor(sm, off);
  if (lane == 0) red[4 + wv] = sm;
  __syncthreads();
  float tot = red[4] + red[5] + red[6] + red[7];
  alpha[tid] = e / tot;
  const float ml = (float)((const int*)(ws + oLens))[b];
  const float ll = (float)((const int*)(ws + oLens + 512))[b];
  const float al = (float)((const int*)(ws + oLens + 1024))[b];
  __syncthreads();
  const float* memv = (const float*)(ws + oMemV) + (size_t)b * S_ * 600;
  float* iT = (float*)(ws + oIT);
  const int d0 = dh * 301, d1 = dh ? 601 : 301;
  for (int d = d0 + tid; d < d1; d += 256) {
    float acc = 0.f;
    if (d < 600) {
      for (int s = 0; s < 256; ++s) acc += alpha[s] * memv[(size_t)s * 600 + d];
    } else {
      for (int s = 0; s < 256; ++s) {
        float p = (float)s;
        bool inl = p < ll;
        bool inr = (p >= ll + al) && (p < ml);
        float u = inl ? (p - ll) : (inr ? (p - ll - al + 1.f) : 0.f);
        acc += alpha[s] * u;
      }
    }
    iT[d * 128 + b] = acc;
  }
}

// ---------------- K7: GRU gi (once) ----------------
__global__ __launch_bounds__(256) void gi_kernel(const float* __restrict__ Wih,
                                                 const float* __restrict__ bih,
                                                 char* __restrict__ ws) {
  int idx = blockIdx.x * 256 + threadIdx.x;
  int r = idx >> 7, b = idx & 127;
  if (r >= 900) return;
  const float* iT = (const float*)(ws + oIT);
  const float* wr = Wih + (size_t)r * 601;
  float acc = bih[r];
  for (int d = 0; d < 601; ++d) acc += iT[d * 128 + b] * wr[d];
  ((float*)(ws + oGi))[r * 128 + b] = acc;
}

// ---------------- K8: GRU gh (per hop) ----------------
__global__ __launch_bounds__(256) void gh_kernel(const float* __restrict__ Whh,
                                                 const float* __restrict__ bhh,
                                                 char* __restrict__ ws) {
  int idx = blockIdx.x * 256 + threadIdx.x;
  int r = idx >> 7, b = idx & 127;
  if (r >= 900) return;
  const float* et = (const float*)(ws + oEt);
  const float* wr = Whh + (size_t)r * 300;
  float acc = bhh[r];
  for (int u = 0; u < 300; ++u) acc += et[u * 128 + b] * wr[u];
  ((float*)(ws + oGh))[r * 128 + b] = acc;
}

// ---------------- K9: GRU update (per hop) ----------------
__global__ __launch_bounds__(256) void up_kernel(char* __restrict__ ws) {
  int idx = blockIdx.x * 256 + threadIdx.x;
  int u = idx >> 7, b = idx & 127;
  if (u >= 300) return;
  const float* gi = (const float*)(ws + oGi);
  const float* gh = (const float*)(ws + oGh);
  float* et = (float*)(ws + oEt);
  float rr = sigm(gi[u * 128 + b] + gh[u * 128 + b]);
  float zz = sigm(gi[(300 + u) * 128 + b] + gh[(300 + u) * 128 + b]);
  float nn = tanh_f(gi[(600 + u) * 128 + b] + rr * gh[(600 + u) * 128 + b]);
  float old = et[u * 128 + b];
  et[u * 128 + b] = (1.f - zz) * nn + zz * old;
}

// ---------------- K10: dense head ----------------
__global__ __launch_bounds__(384) void dense_kernel(const float* __restrict__ dW,
                                                    const float* __restrict__ dB,
                                                    float* __restrict__ out,
                                                    const char* __restrict__ ws) {
  int tid = threadIdx.x;
  if (tid >= 384) return;
  int b = tid / 3, c = tid - 3 * (tid / 3);
  const float* et = (const float*)(ws + oEt);
  float acc = dB[c];
  const float* wr = dW + c * 300;
  for (int u = 0; u < 300; ++u) acc += et[u * 128 + b] * wr[u];
  out[b * 3 + c] = acc;
}

extern "C" void kernel_launch(void* const* d_in, const int* in_sizes, int n_in,
                              void* d_out, int out_size, void* d_ws, size_t ws_size,
                              hipStream_t stream) {
  const int* text = (const int*)d_in[0];
  const int* aspect = (const int*)d_in[1];
  const int* leftc = (const int*)d_in[2];
  const float* emb = (const float*)d_in[3];
  const float* WihF = (const float*)d_in[4];
  const float* WhhF = (const float*)d_in[5];
  const float* bihF = (const float*)d_in[6];
  const float* bhhF = (const float*)d_in[7];
  const float* WihB = (const float*)d_in[8];
  const float* WhhB = (const float*)d_in[9];
  const float* bihB = (const float*)d_in[10];
  const float* bhhB = (const float*)d_in[11];
  const float* attW = (const float*)d_in[12];
  const float* gruWih = (const float*)d_in[14];
  const float* gruWhh = (const float*)d_in[15];
  const float* gruBih = (const float*)d_in[16];
  const float* gruBhh = (const float*)d_in[17];
  const float* denseW = (const float*)d_in[18];
  const float* denseB = (const float*)d_in[19];
  float* out = (float*)d_out;
  char* ws = (char*)d_ws;
  if (ws_size < WS_NEED) return;

  init_kernel<<<67, 256, 0, stream>>>(text, aspect, leftc, ws);
  pack_kernel<<<6420, 256, 0, stream>>>(WihF, WhhF, bihF, bhhF, WihB, WhhB, bihB, bhhB, ws);
  gather_kernel<<<2 * B_ * S_, KPAD, 0, stream>>>(text, emb, ws);
  lstm_kernel<<<NBLK, 256, 0, stream>>>(ws);
  score_kernel<<<2 * B_, 256, 0, stream>>>(attW, ws);
  attn_kernel<<<2 * B_, 256, 0, stream>>>(ws);
  gi_kernel<<<450, 256, 0, stream>>>(gruWih, gruBih, ws);
  for (int h = 0; h < 3; ++h) {
    gh_kernel<<<450, 256, 0, stream>>>(gruWhh, gruBhh, ws);
    up_kernel<<<150, 256, 0, stream>>>(ws);
  }
  dense_kernel<<<1, 384, 0, stream>>>(denseW, denseB, out, ws);
}

// Round 9
// 1816.005 us; speedup vs baseline: 1.5500x; 1.4244x over previous
//
#include <hip/hip_runtime.h>
#include <hip/hip_bf16.h>
#include <math.h>

#define B_ 128
#define S_ 256
#define A_ 8
#define E_ 300
#define H_ 300
#define KPAD 320
#define NGU 16     // unit groups per direction
#define NCOL 80    // padded gate-cols per unit group (<=80 real)
#define HROW 328   // LDS row stride (u16) for h panel (320 + 8 pad)
#define NBLK 128   // 8 pods (dir2 x gb4) x 16 unit-groups
#define GST 82     // gatesLds row stride (f32): 2-way (free) banks on C-staging

typedef unsigned short u16;
typedef unsigned int u32;
typedef unsigned long long u64;
typedef __attribute__((ext_vector_type(8))) short short8;
typedef __attribute__((ext_vector_type(4))) float floatx4;
typedef __attribute__((ext_vector_type(4))) unsigned int u32x4;

#define MFMA16(a, b, c) __builtin_amdgcn_mfma_f32_16x16x32_bf16((a), (b), (c), 0, 0, 0)

__device__ __host__ __forceinline__ int gu_cnt(int g) { return g < 6 ? 20 : 18; }
__device__ __host__ __forceinline__ int gu_u0(int g) { return g < 6 ? 20 * g : 120 + 18 * (g - 6); }

// ---- workspace layout (bytes) ----
static constexpr size_t oLens = 0;                       // mem_len[128], left_len[128], asp_len[128]
static constexpr size_t oFlg  = 1536;                    // PLAIN flags [pod8][slot16] @16B (2048B)
static constexpr size_t oH    = 4096;                    // h bf16 (sc1 copy) [par2][dir2][128][320] = 327680
static constexpr size_t oMemX = 331776;                  // x bf16 [dir2][128][256][320] = 41943040
static constexpr size_t oWp   = 42274816;                // packed W bf16 [2][16][80][640] = 3276800
static constexpr size_t oBp   = 45551616;                // packed bias f32 [2][16][80] = 10240
static constexpr size_t oMemV = 45561856;                // locationed memory v f32 [128][256][600] = 78643200
static constexpr size_t oIT   = 124205056;               // i^T f32 [601][128]
static constexpr size_t oGi   = 124512768;               // gi^T f32 [900][128]
static constexpr size_t oGh   = 124973568;               // gh^T f32 [900][128]
static constexpr size_t oEt   = 125434368;               // et^T f32 [300][128]
static constexpr size_t oSc   = 125587968;               // scores f32 [128][256]
static constexpr size_t oMirr = 125719040;               // MIRROR flags (sc1) [pod8][slot16] @16B (2048B)
static constexpr size_t oHL2  = 125721088;               // h bf16 (plain/L2 copy) = 327680
static constexpr size_t WS_NEED = 126048768;             // ~120 MB

__device__ __forceinline__ u16 f2bf(float f) {
  union { float f; unsigned u; } v; v.f = f;
  unsigned r = (v.u + 0x7FFFu + ((v.u >> 16) & 1u)) >> 16;
  return (u16)r;
}
__device__ __forceinline__ float sigm(float x) { return 1.f / (1.f + __expf(-x)); }
__device__ __forceinline__ float tanh_f(float x) {
  x = fminf(15.f, fmaxf(-15.f, x));
  float e = __expf(2.f * x);
  return (e - 1.f) / (e + 1.f);
}
__device__ __forceinline__ u32 ld_sc0(const u32* p) {   // L1-bypass load (reads own L2)
  u32 v;
  asm volatile("global_load_dword %0, %1, off sc0\n\ts_waitcnt vmcnt(0)"
               : "=v"(v) : "v"(p) : "memory");
  return v;
}

// ---------------- K1: lengths + zero init ----------------
__global__ __launch_bounds__(256) void init_kernel(const int* __restrict__ text,
                                                   const int* __restrict__ aspect,
                                                   const int* __restrict__ leftc,
                                                   char* __restrict__ ws) {
  const int bid = blockIdx.x, tid = threadIdx.x;
  if (bid == 0) {
    if (tid < B_) {
      int c = 0; const int* p = text + tid * S_;
      for (int s = 0; s < S_; ++s) c += (p[s] != 0);
      ((int*)(ws + oLens))[tid] = c;
    }
  } else if (bid == 1) {
    if (tid < B_) {
      int c = 0; const int* p = leftc + tid * S_;
      for (int s = 0; s < S_; ++s) c += (p[s] != 0);
      ((int*)(ws + oLens + 512))[tid] = c;
    }
  } else if (bid == 2) {
    if (tid < B_) {
      int c = 0; const int* p = aspect + tid * A_;
      for (int s = 0; s < A_; ++s) c += (p[s] != 0);
      ((int*)(ws + oLens + 1024))[tid] = c;
    }
  } else {
    const int F1 = 512, F2 = 512, HW = 81920, H2 = 81920, EW = 38400;
    const int total = F1 + F2 + HW + H2 + EW;
    for (int i = (bid - 3) * 256 + tid; i < total; i += 64 * 256) {
      int j = i;
      if (j < F1)            { ((u32*)(ws + oFlg))[j] = 0u; continue; }  j -= F1;
      if (j < F2)            { ((u32*)(ws + oMirr))[j] = 0u; continue; } j -= F2;
      if (j < HW)            { ((u32*)(ws + oH))[j] = 0u; continue; }    j -= HW;
      if (j < H2)            { ((u32*)(ws + oHL2))[j] = 0u; continue; }  j -= H2;
      ((u32*)(ws + oEt))[j] = 0u;
    }
  }
}

// ---------------- K2: weight/bias pre-pack to bf16 ----------------
__global__ __launch_bounds__(256) void pack_kernel(
    const float* __restrict__ WihF, const float* __restrict__ WhhF,
    const float* __restrict__ bihF, const float* __restrict__ bhhF,
    const float* __restrict__ WihB, const float* __restrict__ WhhB,
    const float* __restrict__ bihB, const float* __restrict__ bhhB,
    char* __restrict__ ws) {
  const int WTOT = 2 * NGU * NCOL * 640;
  int idx = blockIdx.x * 256 + threadIdx.x;
  if (idx < WTOT) {
    int k = idx % 640;
    int n = (idx / 640) % NCOL;
    int g = (idx / (640 * NCOL)) % NGU;
    int dir = idx / (640 * NCOL * NGU);
    float v = 0.f;
    const int cnt = gu_cnt(g), u0 = gu_u0(g);
    if (n < cnt * 4) {
      int col = (n & 3) * 300 + u0 + (n >> 2);
      const float* Wih = dir ? WihB : WihF;
      const float* Whh = dir ? WhhB : WhhF;
      if (k < 300)                  v = Wih[(size_t)col * 300 + k];
      else if (k >= 320 && k < 620) v = Whh[(size_t)col * 300 + (k - 320)];
    }
    ((u16*)(ws + oWp))[idx] = f2bf(v);
  } else {
    int j = idx - WTOT;
    if (j < 2 * NGU * NCOL) {
      int n = j % NCOL; int g = (j / NCOL) % NGU; int dir = j / (NCOL * NGU);
      float v = 0.f;
      const int cnt = gu_cnt(g), u0 = gu_u0(g);
      if (n < cnt * 4) {
        int col = (n & 3) * 300 + u0 + (n >> 2);
        v = (dir ? bihB : bihF)[col] + (dir ? bhhB : bhhF)[col];
      }
      ((float*)(ws + oBp))[j] = v;
    }
  }
}

// ---------------- K3: embedding gather (bwd dir pre-reversed) ----------------
__global__ __launch_bounds__(KPAD) void gather_kernel(const int* __restrict__ text,
                                                      const float* __restrict__ emb,
                                                      char* __restrict__ ws) {
  const int bid = blockIdx.x;
  const int t = bid & 255;
  const int b = (bid >> 8) & 127;
  const int dir = bid >> 15;
  const int len = ((const int*)(ws + oLens))[b];
  const int tp = (dir == 0) ? t : ((t < len) ? (len - 1 - t) : t);
  const int tok = text[b * S_ + tp];
  u16* dst = (u16*)(ws + oMemX) + ((size_t)((dir * B_ + b) * S_ + t)) * KPAD;
  const float* src = emb + (size_t)tok * E_;
  const int k = threadIdx.x;
  float v = (k < E_) ? src[k] : 0.f;
  dst[k] = f2bf(v);
}

// ---------------- K4: persistent BiLSTM — BASELINE protocol + W in registers ----------------
// Protocol scoreboard (R4-R7): flags+drains(1537) beat tagged(1798/1730),
// direct-frags(2472), mirror-only(2217) -> the baseline exchange is kept
// VERBATIM (optimistic XCD-local plain flags/panels + sc1 mirror fallback,
// dual publish, drain-before-flag). The single graft is R5's verified win:
// W fragments live in VGPRs (loaded once from packed global W). Wlds deleted
// (-103KB LDS, -240 of ~280 per-step ds_read_b128, bank conflicts -77% when
// measured on R4->R5). gatesLds stride 81->82 (R5-proven, kills a 4-way
// conflict on C-staging writes).
__global__ __launch_bounds__(256, 1) void lstm_kernel(char* __restrict__ ws) {
  const int bid = (int)blockIdx.x;
  const int pod = bid & 7;              // {dir, gb}
  const int dir = pod >> 2;
  const int gb  = pod & 3;
  const int g   = bid >> 3;             // unit group 0..15
  const int cnt = gu_cnt(g), u0 = gu_u0(g);
  const int npair = cnt >> 1;           // 10 or 9
  const int tid = threadIdx.x;
  const int wv = tid >> 6;              // 0..3
  const int lane = tid & 63;
  const int quad = lane >> 4;
  const int l16 = lane & 15;
  const int Mtile = wv >> 1;            // rows [Mtile*16, +16)
  const int nt0 = (wv & 1) ? 3 : 0;     // N-tile set {0,1,2} or {3,4}
  const int ntc = (wv & 1) ? 2 : 3;

  const u16* __restrict__ Wg = (const u16*)(ws + oWp) + (size_t)(dir * NGU + g) * NCOL * 640;
  const float* __restrict__ Bpk = (const float*)(ws + oBp) + (dir * NGU + g) * NCOL;
  const u16* __restrict__ memx = (const u16*)(ws + oMemX) + (size_t)dir * B_ * S_ * KPAD;
  const u16* __restrict__ hb16 = (const u16*)(ws + oH);
  u32* __restrict__ hb32 = (u32*)(ws + oH);
  const u16* __restrict__ hl16 = (const u16*)(ws + oHL2);
  u32* __restrict__ hl32 = (u32*)(ws + oHL2);
  float* __restrict__ memv = (float*)(ws + oMemV);
  u32* __restrict__ flagsP = (u32*)(ws + oFlg) + (size_t)pod * 64;   // plain, 16 slots @16B
  u32* __restrict__ flagsM = (u32*)(ws + oMirr) + (size_t)pod * 64;  // sc1 mirror

  __shared__ __align__(16) u16 hLds[32 * HROW];            // 20992 B
  __shared__ float gatesLds[32 * GST];                     // 10496 B
  __shared__ float cS[640];
  __shared__ float hS[640];
  __shared__ float biasS[NCOL];
  __shared__ int lenS[32], llS[32], alS[32];
  __shared__ int remoteS;

  for (int i = tid; i < 640; i += 256) { cS[i] = 0.f; hS[i] = 0.f; }
  if (tid < NCOL) biasS[tid] = Bpk[tid];
  if (tid < 32) {
    lenS[tid] = ((const int*)(ws + oLens))[gb * 32 + tid];
    llS[tid]  = ((const int*)(ws + oLens + 512))[gb * 32 + tid];
    alS[tid]  = ((const int*)(ws + oLens + 1024))[gb * 32 + tid];
  }
  if (tid == 0) remoteS = 0;

  // W fragments -> registers (once). Mapping identical to the old Wlds reads:
  // col (nt0+j)*16 + l16, k = quad*8 + kk*32 (+320 for the h-part).
  short8 wx[10][3], wh[10][3];
  #pragma unroll
  for (int kk = 0; kk < 10; ++kk) {
    #pragma unroll
    for (int j = 0; j < 3; ++j) {
      if (j < ntc) {
        const u16* base = Wg + (size_t)((nt0 + j) * 16 + l16) * 640 + quad * 8;
        wx[kk][j] = *(const short8*)(base + kk * 32);
        wh[kk][j] = *(const short8*)(base + 320 + kk * 32);
      }
    }
  }
  __syncthreads();

  const int row = gb * 32 + Mtile * 16 + l16;   // global batch row for A-frags

  // per-thread staging geometry: 1280 x 16B chunks, 5/thread
  int eoff[5]; u16* ldst[5];
  #pragma unroll
  for (int it = 0; it < 5; ++it) {
    int e = (it * 256 + tid) * 8;
    int r = e / KPAD, c = e - r * KPAD;
    eoff[it] = e;
    ldst[it] = hLds + r * HROW + c;
  }
  const u16* hA = hLds + (Mtile * 16 + l16) * HROW + quad * 8;

  // prefetch x fragments for t = 0
  short8 xv[10];
  {
    const u16* xr = memx + ((size_t)row * S_) * KPAD + quad * 8;
    #pragma unroll
    for (int kk = 0; kk < 10; ++kk) xv[kk] = *(const short8*)(xr + kk * 32);
  }

  for (int t = 0; t < S_; ++t) {
    if (t > 0) {
      if (wv == 0) {
        const u32 target = (u32)t;
        int spin = 0;
        while (true) {
          u32 f = 0xFFFFFFFFu;
          const int rm = *(volatile int*)&remoteS;
          if (lane < NGU)
            f = rm ? __hip_atomic_load(&flagsM[lane * 4], __ATOMIC_RELAXED, __HIP_MEMORY_SCOPE_AGENT)
                   : ld_sc0(&flagsP[lane * 4]);
          if (__all((int)(f >= target))) break;
          ++spin;
          if (!rm && spin > 64 && (spin & 15) == 0) {
            // if the sc1 mirror is ahead of the plain copy, our pod spans XCDs
            u32 fm = 0u, fp = 0xFFFFFFFFu;
            if (lane < NGU) {
              fm = __hip_atomic_load(&flagsM[lane * 4], __ATOMIC_RELAXED, __HIP_MEMORY_SCOPE_AGENT);
              fp = ld_sc0(&flagsP[lane * 4]);
            }
            if (__any((int)(fm > fp))) { if (lane == 0) *(volatile int*)&remoteS = 1; }
          }
          if (rm) __builtin_amdgcn_s_sleep(1);
        }
      }
      __syncthreads();
      __builtin_amdgcn_fence(__ATOMIC_ACQUIRE, "workgroup");
    }

    // stage the pod's h panel -> LDS (sc0 from shared L2, or sc1 fallback)
    const int rem = *(volatile int*)&remoteS;
    u32x4 hstash[5];
    {
      const size_t pbase = (((size_t)(t & 1) * 2 + dir) * B_ + gb * 32) * KPAD;
      if (rem) {
        const u16* hpan = hb16 + pbase;
        #pragma unroll
        for (int it = 0; it < 5; ++it)
          asm volatile("global_load_dwordx4 %0, %1, off sc1"
                       : "=v"(hstash[it]) : "v"(hpan + eoff[it]) : "memory");
      } else {
        const u16* hpan = hl16 + pbase;
        #pragma unroll
        for (int it = 0; it < 5; ++it)
          asm volatile("global_load_dwordx4 %0, %1, off sc0"
                       : "=v"(hstash[it]) : "v"(hpan + eoff[it]) : "memory");
      }
    }

    floatx4 acc[3];
    acc[0] = (floatx4){0.f, 0.f, 0.f, 0.f}; acc[1] = acc[0]; acc[2] = acc[0];
    // x-part (prefetched regs, W in regs) — overlaps the h-load round trip
    #pragma unroll
    for (int kk = 0; kk < 10; ++kk) {
      #pragma unroll
      for (int j = 0; j < 3; ++j) {
        if (j < ntc)
          acc[j] = MFMA16(xv[kk], wx[kk][j], acc[j]);
      }
    }

    // land h into LDS
    asm volatile("s_waitcnt vmcnt(0)" ::: "memory");
    #pragma unroll
    for (int it = 0; it < 5; ++it) *(u32x4*)ldst[it] = hstash[it];
    __syncthreads();

    // h-part: A-frags from LDS, B-frags from registers
    #pragma unroll
    for (int kk = 0; kk < 10; ++kk) {
      const short8 av = *(const short8*)(hA + kk * 32);
      #pragma unroll
      for (int j = 0; j < 3; ++j) {
        if (j < ntc)
          acc[j] = MFMA16(av, wh[kk][j], acc[j]);
      }
    }

    // stage gates to LDS (C layout: col=lane&15, row=quad*4+reg)
    #pragma unroll
    for (int j = 0; j < 3; ++j) {
      if (j < ntc) {
        const int colb = (nt0 + j) * 16 + l16;
        const int rb = Mtile * 16 + quad * 4;
        #pragma unroll
        for (int r = 0; r < 4; ++r)
          gatesLds[(rb + r) * GST + colb] = acc[j][r];
      }
    }
    __syncthreads();

    // elementwise LSTM cell: 32 rows * npair unit-pairs
    const int nxt = (t + 1) & 1;
    float2 sv[2]; float* sa[2]; bool sval[2];
    #pragma unroll
    for (int z = 0; z < 2; ++z) {
      const int it = tid + z * 256;
      sval[z] = (it < 32 * npair);
      if (!sval[z]) continue;
      const int bl = it & 31;
      const int pl = it >> 5;
      const int ul0 = pl * 2;
      const int len = lenS[bl];
      const bool m = (t < len);
      const float* gp = gatesLds + bl * GST + ul0 * 4;
      const float* bp = biasS + ul0 * 4;
      float h0K, h1K, h0N, h1N;
      {
        float ig = sigm(gp[0] + bp[0]);
        float fg = sigm(gp[1] + bp[1]);
        float gt = tanh_f(gp[2] + bp[2]);
        float og = sigm(gp[3] + bp[3]);
        float cOld = cS[ul0 * 32 + bl], hOld = hS[ul0 * 32 + bl];
        float cNew = fg * cOld + ig * gt;
        float hNew = og * tanh_f(cNew);
        cS[ul0 * 32 + bl] = m ? cNew : cOld;
        h0K = m ? hNew : hOld;
        hS[ul0 * 32 + bl] = h0K;
        h0N = m ? hNew : 0.f;
      }
      {
        float ig = sigm(gp[4] + bp[4]);
        float fg = sigm(gp[5] + bp[5]);
        float gt = tanh_f(gp[6] + bp[6]);
        float og = sigm(gp[7] + bp[7]);
        float cOld = cS[(ul0 + 1) * 32 + bl], hOld = hS[(ul0 + 1) * 32 + bl];
        float cNew = fg * cOld + ig * gt;
        float hNew = og * tanh_f(cNew);
        cS[(ul0 + 1) * 32 + bl] = m ? cNew : cOld;
        h1K = m ? hNew : hOld;
        hS[(ul0 + 1) * 32 + bl] = h1K;
        h1N = m ? hNew : 0.f;
      }
      const int bglob = gb * 32 + bl;
      const size_t hidx = (((size_t)nxt * 2 + dir) * B_ + bglob) * 160 + ((u0 + ul0) >> 1);
      u32 packed = (u32)f2bf(h0K) | ((u32)f2bf(h1K) << 16);
      hl32[hidx] = packed;                                        // plain copy (own L2)
      __hip_atomic_store(&hb32[hidx], packed,
                         __ATOMIC_RELAXED, __HIP_MEMORY_SCOPE_AGENT);  // sc1 copy
      int pos = (dir == 0) ? t : (m ? (len - 1 - t) : t);
      float ml = (float)len, ll = (float)llS[bl], al = (float)alS[bl];
      float p = (float)pos;
      float wl;
      if (p < ll) wl = 1.f - (ll - p) / ml;
      else if ((p >= ll + al) && (p < ml)) wl = 1.f - (p - ll - al + 1.f) / ml;
      else wl = 1.f;
      sv[z] = make_float2(h0N * wl, h1N * wl);
      sa[z] = &memv[((size_t)bglob * S_ + pos) * 600 + dir * 300 + u0 + ul0];
    }

    __builtin_amdgcn_fence(__ATOMIC_RELEASE, "workgroup");
    __syncthreads();  // vmcnt(0) drain: both h copies are ack'd
    if (tid == 0) {
      *(volatile u32*)&flagsP[g * 4] = (u32)(t + 1);               // plain flag (own L2)
      __hip_atomic_store(&flagsM[g * 4], (u32)(t + 1),
                         __ATOMIC_RELAXED, __HIP_MEMORY_SCOPE_AGENT);  // sc1 mirror
    }

    // deferred memv stores + next-step x prefetch — overlap the poll window
    #pragma unroll
    for (int z = 0; z < 2; ++z)
      if (sval[z]) *(float2*)sa[z] = sv[z];
    if (t + 1 < S_) {
      const u16* xr = memx + ((size_t)row * S_ + (t + 1)) * KPAD + quad * 8;
      #pragma unroll
      for (int kk = 0; kk < 10; ++kk) xv[kk] = *(const short8*)(xr + kk * 32);
    }
  }
}

// ---------------- K5: attention scores ----------------
__global__ __launch_bounds__(256) void score_kernel(const float* __restrict__ attW,
                                                    char* __restrict__ ws) {
  const int bid = blockIdx.x;
  const int b = bid >> 1, sh = bid & 1;
  const int tid = threadIdx.x, wv = tid >> 6, lane = tid & 63;
  __shared__ float aW[601];
  for (int i = tid; i < 601; i += 256) aW[i] = attW[i];
  const float* memv = (const float*)(ws + oMemV) + (size_t)b * S_ * 600;
  const float ml = (float)((const int*)(ws + oLens))[b];
  const float ll = (float)((const int*)(ws + oLens + 512))[b];
  const float al = (float)((const int*)(ws + oLens + 1024))[b];
  __syncthreads();
  float* scg = (float*)(ws + oSc) + b * S_;
  for (int s = sh * 128 + wv; s < sh * 128 + 128; s += 4) {
    const float* rowp = memv + (size_t)s * 600;
    float acc = 0.f;
    for (int d = lane; d < 600; d += 64) acc += rowp[d] * aW[d];
    for (int off = 32; off; off >>= 1) acc += __shfl_xor(acc, off);
    if (lane == 0) {
      float p = (float)s;
      bool inl = p < ll;
      bool inr = (p >= ll + al) && (p < ml);
      float u = inl ? (p - ll) : (inr ? (p - ll - al + 1.f) : 0.f);
      scg[s] = acc + u * aW[600];
    }
  }
}

// ---------------- K6: softmax + weighted sum -> i^T ----------------
__global__ __launch_bounds__(256) void attn_kernel(char* __restrict__ ws) {
  const int bid = blockIdx.x;
  const int b = bid >> 1, dh = bid & 1;
  const int tid = threadIdx.x, wv = tid >> 6, lane = tid & 63;
  __shared__ float alpha[256];
  __shared__ float red[8];
  const float* scg = (const float*)(ws + oSc) + b * S_;
  float v = scg[tid];
  float mx = v;
  for (int off = 32; off; off >>= 1) mx = fmaxf(mx, __shfl_xor(mx, off));
  if (lane == 0) red[wv] = mx;
  __syncthreads();
  mx = fmaxf(fmaxf(red[0], red[1]), fmaxf(red[2], red[3]));
  float e = __expf(v - mx);
  float sm = e;
  for (int off = 32; off; off >>= 1) sm += __shfl_xor(sm, off);
  if (lane == 0) red[4 + wv] = sm;
  __syncthreads();
  float tot = red[4] + red[5] + red[6] + red[7];
  alpha[tid] = e / tot;
  const float ml = (float)((const int*)(ws + oLens))[b];
  const float ll = (float)((const int*)(ws + oLens + 512))[b];
  const float al = (float)((const int*)(ws + oLens + 1024))[b];
  __syncthreads();
  const float* memv = (const float*)(ws + oMemV) + (size_t)b * S_ * 600;
  float* iT = (float*)(ws + oIT);
  const int d0 = dh * 301, d1 = dh ? 601 : 301;
  for (int d = d0 + tid; d < d1; d += 256) {
    float acc = 0.f;
    if (d < 600) {
      for (int s = 0; s < 256; ++s) acc += alpha[s] * memv[(size_t)s * 600 + d];
    } else {
      for (int s = 0; s < 256; ++s) {
        float p = (float)s;
        bool inl = p < ll;
        bool inr = (p >= ll + al) && (p < ml);
        float u = inl ? (p - ll) : (inr ? (p - ll - al + 1.f) : 0.f);
        acc += alpha[s] * u;
      }
    }
    iT[d * 128 + b] = acc;
  }
}

// ---------------- K7: GRU gi (once) ----------------
__global__ __launch_bounds__(256) void gi_kernel(const float* __restrict__ Wih,
                                                 const float* __restrict__ bih,
                                                 char* __restrict__ ws) {
  int idx = blockIdx.x * 256 + threadIdx.x;
  int r = idx >> 7, b = idx & 127;
  if (r >= 900) return;
  const float* iT = (const float*)(ws + oIT);
  const float* wr = Wih + (size_t)r * 601;
  float acc = bih[r];
  for (int d = 0; d < 601; ++d) acc += iT[d * 128 + b] * wr[d];
  ((float*)(ws + oGi))[r * 128 + b] = acc;
}

// ---------------- K8: GRU gh (per hop) ----------------
__global__ __launch_bounds__(256) void gh_kernel(const float* __restrict__ Whh,
                                                 const float* __restrict__ bhh,
                                                 char* __restrict__ ws) {
  int idx = blockIdx.x * 256 + threadIdx.x;
  int r = idx >> 7, b = idx & 127;
  if (r >= 900) return;
  const float* et = (const float*)(ws + oEt);
  const float* wr = Whh + (size_t)r * 300;
  float acc = bhh[r];
  for (int u = 0; u < 300; ++u) acc += et[u * 128 + b] * wr[u];
  ((float*)(ws + oGh))[r * 128 + b] = acc;
}

// ---------------- K9: GRU update (per hop) ----------------
__global__ __launch_bounds__(256) void up_kernel(char* __restrict__ ws) {
  int idx = blockIdx.x * 256 + threadIdx.x;
  int u = idx >> 7, b = idx & 127;
  if (u >= 300) return;
  const float* gi = (const float*)(ws + oGi);
  const float* gh = (const float*)(ws + oGh);
  float* et = (float*)(ws + oEt);
  float rr = sigm(gi[u * 128 + b] + gh[u * 128 + b]);
  float zz = sigm(gi[(300 + u) * 128 + b] + gh[(300 + u) * 128 + b]);
  float nn = tanh_f(gi[(600 + u) * 128 + b] + rr * gh[(600 + u) * 128 + b]);
  float old = et[u * 128 + b];
  et[u * 128 + b] = (1.f - zz) * nn + zz * old;
}

// ---------------- K10: dense head ----------------
__global__ __launch_bounds__(384) void dense_kernel(const float* __restrict__ dW,
                                                    const float* __restrict__ dB,
                                                    float* __restrict__ out,
                                                    const char* __restrict__ ws) {
  int tid = threadIdx.x;
  if (tid >= 384) return;
  int b = tid / 3, c = tid - 3 * (tid / 3);
  const float* et = (const float*)(ws + oEt);
  float acc = dB[c];
  const float* wr = dW + c * 300;
  for (int u = 0; u < 300; ++u) acc += et[u * 128 + b] * wr[u];
  out[b * 3 + c] = acc;
}

extern "C" void kernel_launch(void* const* d_in, const int* in_sizes, int n_in,
                              void* d_out, int out_size, void* d_ws, size_t ws_size,
                              hipStream_t stream) {
  const int* text = (const int*)d_in[0];
  const int* aspect = (const int*)d_in[1];
  const int* leftc = (const int*)d_in[2];
  const float* emb = (const float*)d_in[3];
  const float* WihF = (const float*)d_in[4];
  const float* WhhF = (const float*)d_in[5];
  const float* bihF = (const float*)d_in[6];
  const float* bhhF = (const float*)d_in[7];
  const float* WihB = (const float*)d_in[8];
  const float* WhhB = (const float*)d_in[9];
  const float* bihB = (const float*)d_in[10];
  const float* bhhB = (const float*)d_in[11];
  const float* attW = (const float*)d_in[12];
  const float* gruWih = (const float*)d_in[14];
  const float* gruWhh = (const float*)d_in[15];
  const float* gruBih = (const float*)d_in[16];
  const float* gruBhh = (const float*)d_in[17];
  const float* denseW = (const float*)d_in[18];
  const float* denseB = (const float*)d_in[19];
  float* out = (float*)d_out;
  char* ws = (char*)d_ws;
  if (ws_size < WS_NEED) return;

  init_kernel<<<67, 256, 0, stream>>>(text, aspect, leftc, ws);
  pack_kernel<<<6420, 256, 0, stream>>>(WihF, WhhF, bihF, bhhF, WihB, WhhB, bihB, bhhB, ws);
  gather_kernel<<<2 * B_ * S_, KPAD, 0, stream>>>(text, emb, ws);
  lstm_kernel<<<NBLK, 256, 0, stream>>>(ws);
  score_kernel<<<2 * B_, 256, 0, stream>>>(attW, ws);
  attn_kernel<<<2 * B_, 256, 0, stream>>>(ws);
  gi_kernel<<<450, 256, 0, stream>>>(gruWih, gruBih, ws);
  for (int h = 0; h < 3; ++h) {
    gh_kernel<<<450, 256, 0, stream>>>(gruWhh, gruBhh, ws);
    up_kernel<<<150, 256, 0, stream>>>(ws);
  }
  dense_kernel<<<1, 384, 0, stream>>>(denseW, denseB, out, ws);
}